// Round 1
// baseline (526.141 us; speedup 1.0000x reference)
//
#include <hip/hip_runtime.h>
#include <hip/hip_bf16.h>
#include <math.h>

typedef __bf16 bf16;
typedef bf16 bf16x8 __attribute__((ext_vector_type(8)));
typedef bf16 bf16x4 __attribute__((ext_vector_type(4)));
typedef float f32x4 __attribute__((ext_vector_type(4)));

#define MFMA16(A,B,C) __builtin_amdgcn_mfma_f32_16x16x32_bf16(A,B,C,0,0,0)

static constexpr int QKV_ELEMS  = 768 * 256;
static constexpr int PROJ_ELEMS = 256 * 256;

// ---- K0: cast weights fp32 -> bf16 into ws ----
__global__ void cvt_weights(const float* __restrict__ qkv_w,
                            const float* __restrict__ proj_w,
                            bf16* __restrict__ wq, bf16* __restrict__ wp) {
    int i = blockIdx.x * 256 + threadIdx.x;
    if (i < QKV_ELEMS) wq[i] = (bf16)qkv_w[i];
    int j = i - QKV_ELEMS;
    if (j >= 0 && j < PROJ_ELEMS) wp[j] = (bf16)proj_w[j];
}

// ---- fused: shift + QKV + window attention + proj + unshift ----
// block = 256 threads (4 waves), one block per (batch, window). grid = 64*64.
__global__ __launch_bounds__(256, 2)
void swin_fused(const float* __restrict__ x,
                const bf16* __restrict__ wqkv,    // [768][256] bf16
                const bf16* __restrict__ wproj,   // [256][256] bf16
                const float* __restrict__ proj_b, // [256]
                const float* __restrict__ pose_g, // [15][15]
                float* __restrict__ out)
{
    // LDS. xbuf doubles as attn-out for the proj phase. q/k region doubles as P.
    __shared__ alignas(16) unsigned char xbuf[64 * 512];   // [64 tok][256 ch] bf16, swz mask7
    __shared__ alignas(16) unsigned char qkbuf[8192];      // q[64][32]+k[64][32] | P[64][64]
    __shared__ alignas(16) unsigned char vtbuf[32 * 128];  // vT [32 d][64 tok] bf16, swz mask7
    __shared__ alignas(16) unsigned char bst[2][6144];     // B-slice staging (dbuf)
    __shared__ float pose[225];

    const int tid  = threadIdx.x;
    const int wave = tid >> 6, lane = tid & 63;
    const int hi   = lane >> 4, lo = lane & 15;
    const int b    = blockIdx.x >> 6;
    const int w    = blockIdx.x & 63;
    const int wh   = w >> 3, wwi = w & 7;
    const bool mlow = (wh == 7), mright = (wwi == 7);
    const f32x4 zero4 = {0.f, 0.f, 0.f, 0.f};

    if (tid < 225) pose[tid] = pose_g[tid];

    // ---- phase 0: x (with cyclic shift -4,-4) -> LDS bf16, swizzled ----
    #pragma unroll 1
    for (int i = 0; i < 16; ++i) {
        int t  = wave + 4 * i;                       // token in window
        int gy = ((wh << 3) + (t >> 3) + 4) & 63;    // shifted coords read x[(y+4)%64]
        int gx = ((wwi << 3) + (t & 7) + 4) & 63;
        const float4 v = *(const float4*)(x + (((b << 6) + gy) * 64 + gx) * 256 + lane * 4);
        bf16x4 bv; bv[0] = (bf16)v.x; bv[1] = (bf16)v.y; bv[2] = (bf16)v.z; bv[3] = (bf16)v.w;
        int chunk = (lane >> 1) ^ (t & 7);
        *(bf16x4*)(xbuf + t * 512 + (chunk << 4) + ((lane & 1) << 3)) = bv;
    }
    __syncthreads();

    auto wrowf = [&](int h, int r) -> int {          // 96-row head-slice -> qkv_w row
        return (r < 32) ? (h * 32 + r)
             : (r < 64) ? (256 + h * 32 + r - 32)
                        : (512 + h * 32 + r - 64);
    };
    auto ldA = [&](int row, int kchunk) -> bf16x8 {  // A-frag from xbuf (x or attn-out)
        return *(const bf16x8*)(xbuf + row * 512 + ((kchunk ^ (row & 7)) << 4));
    };

    bf16x4 st[8][2];                                  // per-head output stash (bf16)

    #pragma unroll 1
    for (int h = 0; h < 8; ++h) {
        // ===== QKV GEMM: [64,256] x [256,96] -> q,k,v for head h =====
        f32x4 acc[6];
        #pragma unroll
        for (int i = 0; i < 6; ++i) acc[i] = zero4;

        uint4 s0, s1;
        { int r = tid >> 2, ck = tid & 3;
          s0 = *(const uint4*)(wqkv + wrowf(h, r) * 256 + 0 * 32 + ck * 8); }
        if (tid < 128) { int c = tid + 256, r = c >> 2, ck = c & 3;
          s1 = *(const uint4*)(wqkv + wrowf(h, r) * 256 + 0 * 32 + ck * 8); }

        #pragma unroll 1
        for (int kk = 0; kk < 8; ++kk) {
            // write staged slice (dbuf: last reader of this buffer was 2 iters ago)
            unsigned char* dst = bst[kk & 1];
            { int r = tid >> 2, ck = tid & 3;
              *(uint4*)(dst + r * 64 + ((ck ^ (r & 3)) << 4)) = s0; }
            if (tid < 128) { int c = tid + 256, r = c >> 2, ck = c & 3;
              *(uint4*)(dst + r * 64 + ((ck ^ (r & 3)) << 4)) = s1; }
            if (kk < 7) {  // issue next-slice global loads early
                int k2 = (kk + 1) * 32;
                { int r = tid >> 2, ck = tid & 3;
                  s0 = *(const uint4*)(wqkv + wrowf(h, r) * 256 + k2 + ck * 8); }
                if (tid < 128) { int c = tid + 256, r = c >> 2, ck = c & 3;
                  s1 = *(const uint4*)(wqkv + wrowf(h, r) * 256 + k2 + ck * 8); }
            }
            __syncthreads();
            const unsigned char* bp = bst[kk & 1];
            bf16x8 a = ldA(16 * wave + lo, kk * 4 + hi);
            #pragma unroll
            for (int nt = 0; nt < 6; ++nt) {
                int br = nt * 16 + lo;
                bf16x8 bb = *(const bf16x8*)(bp + br * 64 + ((hi ^ (br & 3)) << 4));
                acc[nt] = MFMA16(a, bb, acc[nt]);
            }
        }

        // ---- scatter q,k (row-major [tok][d]) and v transposed [d][tok] ----
        // C-layout: lane holds col=lo, rows = 16*wave + hi*4 + r
        #pragma unroll
        for (int nt = 0; nt < 4; ++nt) {
            unsigned char* base = qkbuf + (nt >> 1) * 4096;  // q then k
            int d = (nt & 1) * 16 + lo;
            #pragma unroll
            for (int r = 0; r < 4; ++r) {
                int t = 16 * wave + hi * 4 + r;
                int ch = (d >> 3) ^ (t & 3);
                *(bf16*)(base + t * 64 + (ch << 4) + ((d & 7) << 1)) = (bf16)acc[nt][r];
            }
        }
        #pragma unroll
        for (int nt = 4; nt < 6; ++nt) {
            int d = (nt - 4) * 16 + lo;
            int t0 = 16 * wave + hi * 4;
            bf16x4 pv;
            #pragma unroll
            for (int r = 0; r < 4; ++r) pv[r] = (bf16)acc[nt][r];
            int ch = ((t0 * 2) >> 4) ^ (d & 7);
            *(bf16x4*)(vtbuf + d * 128 + (ch << 4) + ((t0 * 2) & 15)) = pv;
        }
        __syncthreads();   // q,k,vT visible

        // ===== scores = q k^T (K=32, one MFMA k-step) =====
        f32x4 sacc[4];
        #pragma unroll
        for (int i = 0; i < 4; ++i) sacc[i] = zero4;
        {
            int qrow = 16 * wave + lo;
            bf16x8 qa = *(const bf16x8*)(qkbuf + qrow * 64 + ((hi ^ (qrow & 3)) << 4));
            #pragma unroll
            for (int jt = 0; jt < 4; ++jt) {
                int krow = jt * 16 + lo;
                bf16x8 kb = *(const bf16x8*)(qkbuf + 4096 + krow * 64 + ((hi ^ (krow & 3)) << 4));
                sacc[jt] = MFMA16(qa, kb, sacc[jt]);
            }
        }

        // ===== softmax (fp32, in-register; rows live across 16 lanes) =====
        float p[4][4], lrow[4];
        const int i0 = 16 * wave + hi * 4;
        #pragma unroll
        for (int r = 0; r < 4; ++r) {
            int i = i0 + r, ri_ = i >> 3, ci_ = i & 7;
            float mx = -INFINITY;
            #pragma unroll
            for (int jt = 0; jt < 4; ++jt) {
                int j = jt * 16 + lo, rj = j >> 3, cj = j & 7;
                float s = sacc[jt][r] * 0.17677669529663687f
                        + pose[(rj - ri_ + 7) * 15 + (cj - ci_ + 7)];
                if (mlow   && ((ri_ >= 4) != (rj >= 4))) s = -INFINITY;
                if (mright && ((ci_ >= 4) != (cj >= 4))) s = -INFINITY;
                p[jt][r] = s;
                mx = fmaxf(mx, s);
            }
            mx = fmaxf(mx, __shfl_xor(mx, 1));
            mx = fmaxf(mx, __shfl_xor(mx, 2));
            mx = fmaxf(mx, __shfl_xor(mx, 4));
            mx = fmaxf(mx, __shfl_xor(mx, 8));
            float sum = 0.f;
            #pragma unroll
            for (int jt = 0; jt < 4; ++jt) {
                float e = __expf(p[jt][r] - mx);
                p[jt][r] = e; sum += e;
            }
            sum += __shfl_xor(sum, 1);
            sum += __shfl_xor(sum, 2);
            sum += __shfl_xor(sum, 4);
            sum += __shfl_xor(sum, 8);
            lrow[r] = sum;
        }
        __syncthreads();   // all q/k reads done; safe to overlay P

        // ---- P -> bf16 -> LDS ([64][64], pitch 128, swz mask7) ----
        #pragma unroll
        for (int jt = 0; jt < 4; ++jt)
            #pragma unroll
            for (int r = 0; r < 4; ++r) {
                int i = i0 + r, j = jt * 16 + lo;
                int ch = (j >> 3) ^ (i & 7);
                *(bf16*)(qkbuf + i * 128 + (ch << 4) + ((j & 7) << 1)) = (bf16)p[jt][r];
            }
        __syncthreads();

        // ===== PV: [64,64] x [64,32] =====
        f32x4 oacc[2] = {zero4, zero4};
        #pragma unroll
        for (int ks = 0; ks < 2; ++ks) {
            int prow = 16 * wave + lo;
            bf16x8 pa = *(const bf16x8*)(qkbuf + prow * 128 + (((ks * 4 + hi) ^ (prow & 7)) << 4));
            #pragma unroll
            for (int dt = 0; dt < 2; ++dt) {
                int vrow = dt * 16 + lo;
                bf16x8 vb = *(const bf16x8*)(vtbuf + vrow * 128 + (((ks * 4 + hi) ^ (vrow & 7)) << 4));
                oacc[dt] = MFMA16(pa, vb, oacc[dt]);
            }
        }
        #pragma unroll
        for (int dt = 0; dt < 2; ++dt) {
            bf16x4 o;
            #pragma unroll
            for (int r = 0; r < 4; ++r) o[r] = (bf16)(oacc[dt][r] / lrow[r]);
            #pragma unroll
            for (int hh = 0; hh < 8; ++hh) if (hh == h) st[hh][dt] = o;  // static-index stash
        }
        __syncthreads();   // end of head: PV reads of P/vT done
    }

    // ---- x is dead: overlay attn-out [64 tok][256 ch] bf16 into xbuf ----
    #pragma unroll
    for (int h = 0; h < 8; ++h)
        #pragma unroll
        for (int dt = 0; dt < 2; ++dt)
            #pragma unroll
            for (int r = 0; r < 4; ++r) {
                int t = 16 * wave + hi * 4 + r;
                int col = h * 32 + dt * 16 + lo;
                int ch = (col >> 3) ^ (t & 7);
                *(bf16*)(xbuf + t * 512 + (ch << 4) + ((col & 7) << 1)) = st[h][dt][r];
            }
    __syncthreads();

    // ===== proj: [64,256] x [256,256] + bias, fused reverse shift on store =====
    #pragma unroll 1
    for (int nc = 0; nc < 4; ++nc) {
        f32x4 pacc[4];
        #pragma unroll
        for (int i = 0; i < 4; ++i) pacc[i] = zero4;

        uint4 s0;
        { int r = tid >> 2, ck = tid & 3;
          s0 = *(const uint4*)(wproj + (nc * 64 + r) * 256 + 0 * 32 + ck * 8); }

        #pragma unroll 1
        for (int kk = 0; kk < 8; ++kk) {
            unsigned char* dst = bst[kk & 1];
            { int r = tid >> 2, ck = tid & 3;
              *(uint4*)(dst + r * 64 + ((ck ^ (r & 3)) << 4)) = s0; }
            if (kk < 7) { int r = tid >> 2, ck = tid & 3;
              s0 = *(const uint4*)(wproj + (nc * 64 + r) * 256 + (kk + 1) * 32 + ck * 8); }
            __syncthreads();
            const unsigned char* bp = bst[kk & 1];
            bf16x8 a = ldA(16 * wave + lo, kk * 4 + hi);
            #pragma unroll
            for (int nt = 0; nt < 4; ++nt) {
                int br = nt * 16 + lo;
                bf16x8 bb = *(const bf16x8*)(bp + br * 64 + ((hi ^ (br & 3)) << 4));
                pacc[nt] = MFMA16(a, bb, pacc[nt]);
            }
        }
        #pragma unroll
        for (int nt = 0; nt < 4; ++nt) {
            int col = nc * 64 + nt * 16 + lo;
            float pb = proj_b[col];
            #pragma unroll
            for (int r = 0; r < 4; ++r) {
                int t  = 16 * wave + hi * 4 + r;
                int fy = ((wh << 3) + (t >> 3) + 4) & 63;  // reverse roll: shifted ys -> (ys+4)%64
                int fx = ((wwi << 3) + (t & 7) + 4) & 63;
                out[(((b << 6) + fy) * 64 + fx) * 256 + col] = pacc[nt][r] + pb;
            }
        }
    }
}

extern "C" void kernel_launch(void* const* d_in, const int* in_sizes, int n_in,
                              void* d_out, int out_size, void* d_ws, size_t ws_size,
                              hipStream_t stream) {
    const float* x       = (const float*)d_in[0];
    const float* qkv_w   = (const float*)d_in[1];
    const float* proj_w  = (const float*)d_in[2];
    const float* proj_b  = (const float*)d_in[3];
    const float* pos_emb = (const float*)d_in[4];

    bf16* wq = (bf16*)d_ws;               // 768*256 bf16
    bf16* wp = wq + QKV_ELEMS;            // 256*256 bf16  (total 512 KB of ws)

    cvt_weights<<<dim3((QKV_ELEMS + PROJ_ELEMS) / 256), dim3(256), 0, stream>>>(
        qkv_w, proj_w, wq, wp);
    swin_fused<<<dim3(64 * 64), dim3(256), 0, stream>>>(
        x, wq, wp, proj_b, pos_emb, (float*)d_out);
}

// Round 2
// 394.973 us; speedup vs baseline: 1.3321x; 1.3321x over previous
//
#include <hip/hip_runtime.h>
#include <hip/hip_bf16.h>
#include <math.h>

typedef __bf16 bf16;
typedef bf16 bf16x8 __attribute__((ext_vector_type(8)));
typedef bf16 bf16x4 __attribute__((ext_vector_type(4)));
typedef float f32x4 __attribute__((ext_vector_type(4)));

#define MFMA16(A,B,C) __builtin_amdgcn_mfma_f32_16x16x32_bf16(A,B,C,0,0,0)

static constexpr int QKV_ELEMS  = 768 * 256;
static constexpr int PROJ_ELEMS = 256 * 256;

// wave-local LDS ordering fence (cross-lane visibility without __syncthreads)
static __device__ __forceinline__ void lds_fence() {
    asm volatile("s_waitcnt lgkmcnt(0)" ::: "memory");
    __builtin_amdgcn_sched_barrier(0);
}

// ---- K0: cast weights fp32 -> bf16 into ws ----
__global__ void cvt_weights(const float* __restrict__ qkv_w,
                            const float* __restrict__ proj_w,
                            bf16* __restrict__ wq, bf16* __restrict__ wp) {
    int i = blockIdx.x * 256 + threadIdx.x;
    if (i < QKV_ELEMS) wq[i] = (bf16)qkv_w[i];
    int j = i - QKV_ELEMS;
    if (j >= 0 && j < PROJ_ELEMS) wp[j] = (bf16)proj_w[j];
}

// ---- fused: shift + QKV + window attention + proj + unshift ----
// 512 threads = 8 waves; wave w owns head w. One block per (batch, window).
__global__ __launch_bounds__(512, 2)
void swin_fused(const float* __restrict__ x,
                const bf16* __restrict__ wqkv,    // [768][256] bf16
                const bf16* __restrict__ wproj,   // [256][256] bf16
                const float* __restrict__ proj_b, // [256]
                const float* __restrict__ pose_g, // [15][15]
                float* __restrict__ out)
{
    // xbuf: x [64 tok][256 ch] bf16, chunk-swizzled; later overlaid with attn-out.
    __shared__ alignas(16) unsigned char xbuf[64 * 512];
    // per-wave scratch: q[64][32] (4K) + k[64][32] (4K) + vT[32][64] (4K);
    // P[64][64] (8K) overlays q+k.
    __shared__ alignas(16) unsigned char wbuf[8][12288];
    __shared__ float pose[225];

    const int tid  = threadIdx.x;
    const int wave = tid >> 6, lane = tid & 63;
    const int hi   = lane >> 4, lo = lane & 15;
    const int b    = blockIdx.x >> 6;
    const int w    = blockIdx.x & 63;
    const int wh   = w >> 3, wwi = w & 7;
    const bool mlow = (wh == 7), mright = (wwi == 7);
    const f32x4 zero4 = {0.f, 0.f, 0.f, 0.f};

    if (tid < 225) pose[tid] = pose_g[tid];

    // ---- phase 0: x (cyclic shift -4,-4) -> LDS bf16, swizzled ----
    {
        int tok = tid >> 3, c0 = (tid & 7) * 32;
        int gy = ((wh << 3) + (tok >> 3) + 4) & 63;
        int gx = ((wwi << 3) + (tok & 7) + 4) & 63;
        const float* src = x + (((b << 6) + gy) * 64 + gx) * 256 + c0;
        #pragma unroll
        for (int cc = 0; cc < 4; ++cc) {
            float4 v0 = *(const float4*)(src + cc * 8);
            float4 v1 = *(const float4*)(src + cc * 8 + 4);
            bf16x8 bv;
            bv[0] = (bf16)v0.x; bv[1] = (bf16)v0.y; bv[2] = (bf16)v0.z; bv[3] = (bf16)v0.w;
            bv[4] = (bf16)v1.x; bv[5] = (bf16)v1.y; bv[6] = (bf16)v1.z; bv[7] = (bf16)v1.w;
            int chunk = ((c0 >> 3) + cc) ^ (tok & 7);
            *(bf16x8*)(xbuf + tok * 512 + (chunk << 4)) = bv;
        }
    }
    __syncthreads();

    unsigned char* qb = wbuf[wave];
    unsigned char* kb = qb + 4096;
    unsigned char* vb = qb + 8192;
    unsigned char* Pb = qb;          // P overlays q+k after QK^T
    const int h = wave;

    // ===== QKV^T = mfma(A = W rows (global), B = x rows (LDS)) =====
    // C[n = qkv-row][tok]: lane holds col tok = 16*Nt + lo, rows n = 16*Mt + 4*hi + r
    f32x4 acc[6][4];
    #pragma unroll
    for (int Mt = 0; Mt < 6; ++Mt)
        #pragma unroll
        for (int Nt = 0; Nt < 4; ++Nt) acc[Mt][Nt] = zero4;

    #pragma unroll
    for (int kk = 0; kk < 8; ++kk) {
        bf16x8 af[6], bx[4];
        #pragma unroll
        for (int Mt = 0; Mt < 6; ++Mt) {
            int wrow = (Mt >> 1) * 256 + h * 32 + ((Mt & 1) << 4) + lo;  // q|k|v section
            af[Mt] = *(const bf16x8*)(wqkv + wrow * 256 + kk * 32 + hi * 8);
        }
        #pragma unroll
        for (int Nt = 0; Nt < 4; ++Nt) {
            int tok = Nt * 16 + lo;
            bx[Nt] = *(const bf16x8*)(xbuf + tok * 512 + (((kk * 4 + hi) ^ (tok & 7)) << 4));
        }
        #pragma unroll
        for (int Mt = 0; Mt < 6; ++Mt)
            #pragma unroll
            for (int Nt = 0; Nt < 4; ++Nt)
                acc[Mt][Nt] = MFMA16(af[Mt], bx[Nt], acc[Mt][Nt]);
    }

    // ---- q,k vector-stores -> natural [tok][d] (b64, swizzled) ----
    #pragma unroll
    for (int Mt = 0; Mt < 4; ++Mt) {
        unsigned char* base = (Mt < 2) ? qb : kb;
        int chunk_hi = ((Mt & 1) << 1) + (hi >> 1);     // d>>3, d = 16*(Mt&1)+4*hi+r
        #pragma unroll
        for (int Nt = 0; Nt < 4; ++Nt) {
            int tok = Nt * 16 + lo;
            bf16x4 v;
            #pragma unroll
            for (int r = 0; r < 4; ++r) v[r] = (bf16)acc[Mt][Nt][r];
            *(bf16x4*)(base + tok * 64 + ((chunk_hi ^ (tok & 3)) << 4) + ((hi & 1) << 3)) = v;
        }
    }
    // ---- v -> vT [d][tok] (scalar b16, swizzled) ----
    #pragma unroll
    for (int Mt = 4; Mt < 6; ++Mt)
        #pragma unroll
        for (int Nt = 0; Nt < 4; ++Nt) {
            int tok = Nt * 16 + lo;
            #pragma unroll
            for (int r = 0; r < 4; ++r) {
                int d = ((Mt - 4) << 4) + 4 * hi + r;
                *(bf16*)(vb + d * 128 + (((tok >> 3) ^ (d & 7)) << 4) + ((tok & 7) << 1)) =
                    (bf16)acc[Mt][Nt][r];
            }
        }
    lds_fence();

    // ===== S^T = mfma(A = k rows, B = q rows), K = 32 (one step) =====
    // C[j][i]: lane holds col i = 16*it + lo, rows j = 16*jt + 4*hi + r
    f32x4 sacc[4][4];
    {
        bf16x8 ka[4], qa[4];
        #pragma unroll
        for (int t = 0; t < 4; ++t) {
            int j = t * 16 + lo;
            ka[t] = *(const bf16x8*)(kb + j * 64 + ((hi ^ (j & 3)) << 4));
            qa[t] = *(const bf16x8*)(qb + j * 64 + ((hi ^ (j & 3)) << 4));
        }
        #pragma unroll
        for (int jt = 0; jt < 4; ++jt)
            #pragma unroll
            for (int it = 0; it < 4; ++it)
                sacc[jt][it] = MFMA16(ka[jt], qa[it], zero4);
    }

    // ===== softmax over j (rows of S^T) — in-register + 2 shfls =====
    float rinv[4];
    #pragma unroll
    for (int it = 0; it < 4; ++it) {
        float mx = -INFINITY;
        #pragma unroll
        for (int jt = 0; jt < 4; ++jt) {
            bool tilemask = mlow && ((it >= 2) != (jt >= 2));
            bool colmask  = mright && (((lo & 7) >= 4) != (hi & 1));
            #pragma unroll
            for (int r = 0; r < 4; ++r) {
                int drow = 2 * jt + (hi >> 1) - 2 * it - (lo >> 3) + 7;
                int dcol = 4 * (hi & 1) + r - (lo & 7) + 7;
                float s = sacc[jt][it][r] * 0.17677669529663687f + pose[drow * 15 + dcol];
                if (tilemask | colmask) s = -INFINITY;
                sacc[jt][it][r] = s;
                mx = fmaxf(mx, s);
            }
        }
        mx = fmaxf(mx, __shfl_xor(mx, 16));
        mx = fmaxf(mx, __shfl_xor(mx, 32));
        float sum = 0.f;
        #pragma unroll
        for (int jt = 0; jt < 4; ++jt)
            #pragma unroll
            for (int r = 0; r < 4; ++r) {
                float e = __expf(sacc[jt][it][r] - mx);
                sacc[jt][it][r] = e; sum += e;
            }
        sum += __shfl_xor(sum, 16);
        sum += __shfl_xor(sum, 32);
        rinv[it] = 1.0f / sum;
    }

    // ---- P vector-store -> natural [i][j] (b64, swizzled), overlays q+k ----
    #pragma unroll
    for (int jt = 0; jt < 4; ++jt)
        #pragma unroll
        for (int it = 0; it < 4; ++it) {
            int i = it * 16 + lo;
            bf16x4 pv;
            #pragma unroll
            for (int r = 0; r < 4; ++r) pv[r] = (bf16)sacc[jt][it][r];
            int chunk = ((jt << 1) + (hi >> 1)) ^ (i & 7);   // j>>3
            *(bf16x4*)(Pb + i * 128 + (chunk << 4) + ((hi & 1) << 3)) = pv;
        }
    lds_fence();

    // ===== PV^T = mfma(A = vT rows, B = P rows), K = 64 (2 steps) =====
    // C[d][i]: lane holds col i = 16*it + lo, rows d = 16*dMt + 4*hi + r
    f32x4 oacc[2][4];
    #pragma unroll
    for (int dMt = 0; dMt < 2; ++dMt)
        #pragma unroll
        for (int it = 0; it < 4; ++it) oacc[dMt][it] = zero4;
    #pragma unroll
    for (int ks = 0; ks < 2; ++ks) {
        bf16x8 va[2], pr[4];
        #pragma unroll
        for (int dMt = 0; dMt < 2; ++dMt) {
            int d = dMt * 16 + lo;
            va[dMt] = *(const bf16x8*)(vb + d * 128 + (((ks * 4 + hi) ^ (d & 7)) << 4));
        }
        #pragma unroll
        for (int it = 0; it < 4; ++it) {
            int i = it * 16 + lo;
            pr[it] = *(const bf16x8*)(Pb + i * 128 + (((ks * 4 + hi) ^ (i & 7)) << 4));
        }
        #pragma unroll
        for (int dMt = 0; dMt < 2; ++dMt)
            #pragma unroll
            for (int it = 0; it < 4; ++it)
                oacc[dMt][it] = MFMA16(va[dMt], pr[it], oacc[dMt][it]);
    }

    // ---- all waves done reading x -> overlay attn-out into xbuf ----
    __syncthreads();
    #pragma unroll
    for (int dMt = 0; dMt < 2; ++dMt)
        #pragma unroll
        for (int it = 0; it < 4; ++it) {
            int tok = it * 16 + lo;
            bf16x4 v;
            #pragma unroll
            for (int r = 0; r < 4; ++r) v[r] = (bf16)(oacc[dMt][it][r] * rinv[it]);
            int chunk = ((h << 2) + (dMt << 1) + (hi >> 1)) ^ (tok & 7);  // ch>>3
            *(bf16x4*)(xbuf + tok * 512 + (chunk << 4) + ((hi & 1) << 3)) = v;
        }
    __syncthreads();

    // ===== proj: out = ao * Wp^T + bias; wave w does out-ch 32w..32w+31 =====
    f32x4 pacc[4][2];
    #pragma unroll
    for (int Mt = 0; Mt < 4; ++Mt)
        #pragma unroll
        for (int nt = 0; nt < 2; ++nt) pacc[Mt][nt] = zero4;
    #pragma unroll
    for (int kk = 0; kk < 8; ++kk) {
        bf16x8 aA[4], bB[2];
        #pragma unroll
        for (int Mt = 0; Mt < 4; ++Mt) {
            int tok = Mt * 16 + lo;
            aA[Mt] = *(const bf16x8*)(xbuf + tok * 512 + (((kk * 4 + hi) ^ (tok & 7)) << 4));
        }
        #pragma unroll
        for (int nt = 0; nt < 2; ++nt) {
            int c = wave * 32 + nt * 16 + lo;
            bB[nt] = *(const bf16x8*)(wproj + c * 256 + kk * 32 + hi * 8);
        }
        #pragma unroll
        for (int Mt = 0; Mt < 4; ++Mt)
            #pragma unroll
            for (int nt = 0; nt < 2; ++nt)
                pacc[Mt][nt] = MFMA16(aA[Mt], bB[nt], pacc[Mt][nt]);
    }
    #pragma unroll
    for (int nt = 0; nt < 2; ++nt) {
        int c = wave * 32 + nt * 16 + lo;
        float pb2 = proj_b[c];
        #pragma unroll
        for (int Mt = 0; Mt < 4; ++Mt)
            #pragma unroll
            for (int r = 0; r < 4; ++r) {
                int tok = Mt * 16 + 4 * hi + r;
                int fy = ((wh << 3) + (tok >> 3) + 4) & 63;
                int fx = ((wwi << 3) + (tok & 7) + 4) & 63;
                out[(((b << 6) + fy) * 64 + fx) * 256 + c] = pacc[Mt][nt][r] + pb2;
            }
    }
}

extern "C" void kernel_launch(void* const* d_in, const int* in_sizes, int n_in,
                              void* d_out, int out_size, void* d_ws, size_t ws_size,
                              hipStream_t stream) {
    const float* x       = (const float*)d_in[0];
    const float* qkv_w   = (const float*)d_in[1];
    const float* proj_w  = (const float*)d_in[2];
    const float* proj_b  = (const float*)d_in[3];
    const float* pos_emb = (const float*)d_in[4];

    bf16* wq = (bf16*)d_ws;               // 768*256 bf16
    bf16* wp = wq + QKV_ELEMS;            // 256*256 bf16

    cvt_weights<<<dim3((QKV_ELEMS + PROJ_ELEMS) / 256), dim3(256), 0, stream>>>(
        qkv_w, proj_w, wq, wp);
    swin_fused<<<dim3(64 * 64), dim3(512), 0, stream>>>(
        x, wq, wp, proj_b, pos_emb, (float*)d_out);
}